// Round 18
// baseline (33.359 us; speedup 1.0000x reference)
//
#include <hip/hip_runtime.h>
#include <hip/hip_bf16.h>

// Problem constants
#define BB 64
#define LL 4096
#define CC 16
#define PL 128
#define PC 8
#define NPP 64
#define DD 64
#define TSTEP 0.01f

#define KSPLIT 4                    // lt-range split across blocks
#define LT_PER (PL / KSPLIT)        // 32 lt steps per block
#define NCHUNK 4                    // staging pipeline chunks (8 lt each)
#define NT_MAIN 256                 // 4 waves = 2 kk-halves x 2 patch-halves
#define NMB BB                      // one block-column per batch (64 patches)

#define FRAG_U32 (PL * 8 * 256)                       // 1 MB of W3 bf16 frags
#define SPLIT_STRIDE (NMB * 2 * 2 * 64 * 16)          // 262144 floats per split
#define PART_FLT (KSPLIT * SPLIT_STRIDE)              // 4 MB of f32 partials

typedef float f32x4  __attribute__((ext_vector_type(4)));
typedef float f32x16 __attribute__((ext_vector_type(16)));
typedef int   i32x4  __attribute__((ext_vector_type(4)));
typedef short s16x8  __attribute__((ext_vector_type(8)));
typedef unsigned int u32;

__device__ __forceinline__ float silu_f(float z) {      // z * rcp(1+exp(-z))
    return z * __builtin_amdgcn_rcpf(1.0f + __expf(-z));
}
__device__ __forceinline__ u32 pk(float lo, float hi) {
    __hip_bfloat162 p = __float22bfloat162_rn(float2{lo, hi});
    u32 r;
    __builtin_memcpy(&r, &p, 4);
    return r;
}
__device__ __forceinline__ s16x8 as8(i32x4 v) {
    s16x8 r;
    __builtin_memcpy(&r, &v, 16);
    return r;
}
// exchange: a keeps lo-half, gets b's lo into its hi; b gets a's old hi into its lo
__device__ __forceinline__ void plswap(u32& a, u32& b) {
    auto r = __builtin_amdgcn_permlane32_swap(a, b, false, false);
    u32 tmp[2];
    __builtin_memcpy(tmp, &r, 8);
    a = tmp[0]; b = tmp[1];
}

// ---- W3 (8192x64 f32) -> bf16 frags for mfma_32x32x16, in ws (1 MB) ----
// frag m = ltg*8 + kk*4 + ksub*2 + ns ; lane holds W3[k0 + 2j(+1)][ns*32 + (l&31)]
__global__ __launch_bounds__(256) void w3_prep(const float* __restrict__ W3,
                                               u32* __restrict__ wsf) {
    const int tid  = blockIdx.x * 256 + threadIdx.x;    // 65536 threads
    const int lane = tid & 63;
    const int m    = tid >> 6;                          // 0..1023
    const int ns   = m & 1;
    const int ksub = (m >> 1) & 1;
    const int kk   = (m >> 2) & 1;
    const int ltg  = m >> 3;
    const int k0   = ltg * 64 + kk * 32 + ksub * 16 + ((lane >> 5) << 3);
    const int col  = (ns << 5) + (lane & 31);
    u32 q[4];
    #pragma unroll
    for (int jj = 0; jj < 4; ++jj)
        q[jj] = pk(W3[(size_t)(k0 + 2 * jj)     * DD + col],
                   W3[(size_t)(k0 + 2 * jj + 1) * DD + col]);
    i32x4 v; v.x = (int)q[0]; v.y = (int)q[1]; v.z = (int)q[2]; v.w = (int)q[3];
    *(i32x4*)(wsf + (size_t)m * 256 + (lane << 2)) = v;
}

// ---------------------------- fused main kernel ----------------------------
// r17 math (verified 32.2us, absmax 0.125) + PIPELINED STAGING: the x-row
// gather (measured ~11 MB HBM, ~5-6us exposed before the loop) is split into
// 4 chunks of 8 lt; chunk c+1's global loads sit in registers across chunk
// c's loop (the loop is VALU/trans-bound and doesn't use the VMEM pipe).
// Hazards: loop reads only xq[c] (chunks disjoint); arena rewritten only
// after all gathers of the prior chunk (barrier-separated).
// NOTE: no min-waves hint (round 4: forced spills). No device fences (round
// 11: cross-XCD L2 writeback cost ~130us).
__global__ __launch_bounds__(NT_MAIN) void htfe_main(
    const float* __restrict__ x, const int* __restrict__ start_L,
    const int* __restrict__ idx_C, const float* __restrict__ W1,
    const float* __restrict__ b1, const u32* __restrict__ wsf,
    float* __restrict__ part)
{
    // arena: rowbuf (512 rows x 17 f32 = 34816 B) during staging,
    //        kk-reduction accumulators (16384 B) after the main loop.
    __shared__ __align__(64) float arena[512 * 17];
    __shared__ __align__(16) u32   xq[LT_PER * 256];   // [lt][64 p][4] bf16 x packs (32 KB)
    __shared__ __align__(16) u32   cq[256];            // [64 p][4] bf16 c packs
    __shared__ int sStart[64];

    const int t    = threadIdx.x;
    const int lane = t & 63;
    const int w    = t >> 6;
    const int kk   = w >> 1;                 // K-half (which 32 of 64 dh per lt)
    const int ph   = w & 1;                  // patch half
    const int l31  = lane & 31;
    const bool loH = lane < 32;

    const int mb    = blockIdx.x & (NMB - 1);   // = batch b; XCD = mb%8 for all splits
    const int split = blockIdx.x >> 6;          // 0..3
    const int b     = mb;
    const int lt0   = split * LT_PER;

    if (t < 64) sStart[t] = start_L[b * NPP + t];
    const int pGat = t & 63;
    const i32x4 ciA = *(const i32x4*)(idx_C + (size_t)b * NPP * PC + pGat * 8);
    const i32x4 ciB = *(const i32x4*)(idx_C + (size_t)b * NPP * PC + pGat * 8 + 4);
    if (t < 64) {   // static c-feature B-frag region
        cq[t * 4 + 0] = pk((float)ciA.x, (float)ciA.y);
        cq[t * 4 + 1] = pk((float)ciA.z, (float)ciA.w);
        cq[t * 4 + 2] = pk((float)ciB.x, (float)ciB.y);
        cq[t * 4 + 3] = pk((float)ciB.z, (float)ciB.w);
    }
    __syncthreads();

    // ----- staging pipeline helpers (each chunk = 8 lt = 512 rows) -----
    f32x4 rv[8];                              // in-flight rows (32 VGPR)
    const int rowi  = t >> 2;                 // shared per-thread row/quad split
    const int quadi = t & 3;                  // (t*? no: i = q*256+t below)

    auto LOADROWS = [&](int c) {
        #pragma unroll
        for (int q = 0; q < 8; ++q) {
            const int i    = q * 256 + t;     // 2048 float4 units
            const int row  = i >> 2;          // 0..511
            const int quad = i & 3;
            const int pp   = row & 63;
            const int gRow = sStart[pp] + lt0 + c * 8 + (row >> 6);
            rv[q] = *(const f32x4*)(x + ((size_t)b * LL + (size_t)gRow) * CC + quad * 4);
        }
    };
    auto WRITEROWS = [&]() {
        #pragma unroll
        for (int q = 0; q < 8; ++q) {
            const int i    = q * 256 + t;
            const int row  = i >> 2;
            const int quad = i & 3;
            *(f32x4*)(arena + row * 17 + quad * 4) = rv[q];
        }
    };
    auto GATHER = [&](int c) {
        #pragma unroll
        for (int g = 0; g < 2; ++g) {   // rows t and t+256 (same patch = t&63)
            const int rr = g * 256 + t;
            const float* rb = arena + rr * 17;
            int cis[8];
            cis[0]=ciA.x; cis[1]=ciA.y; cis[2]=ciA.z; cis[3]=ciA.w;
            cis[4]=ciB.x; cis[5]=ciB.y; cis[6]=ciB.z; cis[7]=ciB.w;
            u32 qh[4];
            #pragma unroll
            for (int c2 = 0; c2 < 4; ++c2)
                qh[c2] = pk(rb[cis[2 * c2]], rb[cis[2 * c2 + 1]]);
            u32* dst = xq + (c * 8 + (rr >> 6)) * 256 + (rr & 63) * 4;
            i32x4 vh; vh.x=(int)qh[0]; vh.y=(int)qh[1]; vh.z=(int)qh[2]; vh.w=(int)qh[3];
            *(i32x4*)dst = vh;
        }
    };
    (void)rowi; (void)quadi;

    // prologue: chunk 0 staged fully; chunk 1 loads in flight
    LOADROWS(0);
    WRITEROWS();
    __syncthreads();
    GATHER(0);
    LOADROWS(1);
    __syncthreads();

    const int p  = ph * 32 + l31;            // FULL patch id this lane's col owns
    const int dA = kk * 32 + l31;            // A row (d') this lane owns
    const float startPf = (float)sStart[p];

    // ----- GEMM1 A-fragment (W1^T slice), built once -----
    i32x4 a1f0;
    if (loH) {
        a1f0.x = (int)pk(W1[0 * DD + dA], W1[1 * DD + dA]);
        a1f0.y = (int)pk(W1[2 * DD + dA], W1[3 * DD + dA]);
        a1f0.z = (int)pk(W1[4 * DD + dA], W1[5 * DD + dA]);
        a1f0.w = (int)pk(W1[6 * DD + dA], W1[7 * DD + dA]);
    } else {
        a1f0.x = (int)pk(W1[ 9 * DD + dA], W1[10 * DD + dA]);
        a1f0.y = (int)pk(W1[11 * DD + dA], W1[12 * DD + dA]);
        a1f0.z = (int)pk(W1[13 * DD + dA], W1[14 * DD + dA]);
        a1f0.w = (int)pk(W1[15 * DD + dA], W1[16 * DD + dA]);
    }
    // f32 C-operand: hp = b1 + t*W1[8]
    f32x16 cb16, wt16;
    #pragma unroll
    for (int r = 0; r < 16; ++r) {
        const int dr = kk * 32 + (r & 3) + 8 * (r >> 2) + 4 * (lane >> 5);
        wt16[r] = W1[8 * DD + dr];
        cb16[r] = b1[dr];                    // bias ONLY (tf carries start)
    }

    // ----- pipelined main loop: 4 chunks x 8 lt -----
    f32x16 acc0 = {}, acc1 = {};
    const u32* bsrc = wsf + ((size_t)lt0 * 8 + (size_t)kk * 4) * 256 + (lane << 2);
    const u32* xrd     = loH ? (xq + p * 4) : (cq + p * 4);
    const int  xstride = loH ? 256 : 0;

    for (int c = 0; c < NCHUNK; ++c) {
        #pragma unroll 2
        for (int l8 = 0; l8 < 8; ++l8) {
            const int lt = c * 8 + l8;
            const i32x4 bf00 = *(const i32x4*)(bsrc);         // ksub0 ns0
            const i32x4 bf01 = *(const i32x4*)(bsrc + 256);   // ksub0 ns1
            const i32x4 bf10 = *(const i32x4*)(bsrc + 512);   // ksub1 ns0
            const i32x4 bf11 = *(const i32x4*)(bsrc + 768);   // ksub1 ns1
            bsrc += 2048;

            const i32x4 rd = *(const i32x4*)(xrd + (size_t)lt * xstride);

            // GEMM1: hp = W1x^T * [x;c] + (b1 + t*W1[8]), t = (start+lt)*T
            const float tf = (startPf + (float)(lt0 + lt)) * TSTEP;
            f32x16 hp;
            #pragma unroll
            for (int r = 0; r < 16; ++r) hp[r] = cb16[r] + tf * wt16[r];
            hp = __builtin_amdgcn_mfma_f32_32x32x16_bf16(as8(a1f0), as8(rd), hp, 0, 0, 0);

            // silu + pack to bf16 pairs
            u32 P[8];
            #pragma unroll
            for (int j = 0; j < 8; ++j)
                P[j] = pk(silu_f(hp[2 * j]), silu_f(hp[2 * j + 1]));

            // fragment exchange: hpre C/D layout -> GEMM2 A-frag layout (r8)
            plswap(P[0], P[2]); plswap(P[1], P[3]);
            plswap(P[4], P[6]); plswap(P[5], P[7]);
            i32x4 af0; af0.x=(int)P[0]; af0.y=(int)P[1]; af0.z=(int)P[2]; af0.w=(int)P[3];
            i32x4 af1; af1.x=(int)P[4]; af1.y=(int)P[5]; af1.z=(int)P[6]; af1.w=(int)P[7];

            // GEMM2: accumulate both ns slices
            acc0 = __builtin_amdgcn_mfma_f32_32x32x16_bf16(as8(af0), as8(bf00), acc0, 0, 0, 0);
            acc0 = __builtin_amdgcn_mfma_f32_32x32x16_bf16(as8(af1), as8(bf10), acc0, 0, 0, 0);
            acc1 = __builtin_amdgcn_mfma_f32_32x32x16_bf16(as8(af0), as8(bf01), acc1, 0, 0, 0);
            acc1 = __builtin_amdgcn_mfma_f32_32x32x16_bf16(as8(af1), as8(bf11), acc1, 0, 0, 0);
        }
        // pipeline: commit chunk c+1 (in regs) to LDS, prefetch chunk c+2
        if (c < NCHUNK - 1) {
            WRITEROWS();                 // safe: loop reads xq only, not arena
            __syncthreads();
            GATHER(c + 1);
            if (c < NCHUNK - 2) LOADROWS(c + 2);
            __syncthreads();
        }
    }

    // ----- kk-reduction in LDS (arena reused), then one coalesced partial store -----
    f32x16* redacc = (f32x16*)arena;    // [ph][2][64]
    __syncthreads();                    // rowbuf use done; re-purpose arena
    if (kk == 1) {
        redacc[(ph * 2 + 0) * 64 + lane] = acc0;
        redacc[(ph * 2 + 1) * 64 + lane] = acc1;
    }
    __syncthreads();
    if (kk == 0) {
        const f32x16 r0 = redacc[(ph * 2 + 0) * 64 + lane];
        const f32x16 r1 = redacc[(ph * 2 + 1) * 64 + lane];
        float* pd0 = part + ((((size_t)split * NMB + mb) * 2 + ph) * 2 + 0) * 1024 + (lane << 4);
        float* pd1 = pd0 + 1024;
        #pragma unroll
        for (int q = 0; q < 4; ++q) {
            f32x4 o0, o1;
            #pragma unroll
            for (int j = 0; j < 4; ++j) {
                o0[j] = acc0[q * 4 + j] + r0[q * 4 + j];
                o1[j] = acc1[q * 4 + j] + r1[q * 4 + j];
            }
            *(f32x4*)(pd0 + q * 4) = o0;
            *(f32x4*)(pd1 + q * 4) = o1;
        }
    }
}

// ------------- sum KSPLIT partials + bias + SiLU (writes out once) -------------
// Block bid handles mb = bid & 63 -> bid%8 == mb%8 == writer XCD (L2-resident read).
__global__ __launch_bounds__(256) void finish_reduce(const float* __restrict__ part,
                                                     const float* __restrict__ b3,
                                                     float* __restrict__ out) {
    const int bid   = blockIdx.x;            // 256
    const int mb    = bid & 63;
    const int chunk = bid >> 6;              // 0..3
    const int idx10 = chunk * 256 + threadIdx.x;   // 0..1023 within mb
    const int rq   = idx10 & 3;
    const int lane = (idx10 >> 2) & 63;
    const int ns   = (idx10 >> 8) & 1;
    const int ph   = (idx10 >> 9) & 1;
    const int l31  = lane & 31;
    const float* src = part + (((size_t)mb * 2 + ph) * 2 + ns) * 1024 + (lane << 4) + (rq << 2);
    f32x4 s = {0.f, 0.f, 0.f, 0.f};
    #pragma unroll
    for (int sp = 0; sp < KSPLIT; ++sp) {
        const f32x4 v = *(const f32x4*)(src + (size_t)sp * SPLIT_STRIDE);
        s.x += v.x; s.y += v.y; s.z += v.z; s.w += v.w;
    }
    const int col  = (ns << 5) + l31;
    const float bias = b3[col];
    #pragma unroll
    for (int j = 0; j < 4; ++j) {
        // verified 32x32 C/D layout: row=(r&3)+8*(r>>2)+4*(lane>>5), col=lane&31
        const int prow = ph * 32 + j + 8 * rq + 4 * (lane >> 5);
        out[(size_t)(mb * NPP + prow) * DD + col] = silu_f(s[j] + bias);
    }
}

extern "C" void kernel_launch(void* const* d_in, const int* in_sizes, int n_in,
                              void* d_out, int out_size, void* d_ws, size_t ws_size,
                              hipStream_t stream) {
    // inputs: x, start_L, idx_C, W1, b1, W2(unused), b2(unused), W3, b3
    const float* x       = (const float*)d_in[0];
    const int*   start_L = (const int*)  d_in[1];
    const int*   idx_C   = (const int*)  d_in[2];
    const float* W1      = (const float*)d_in[3];
    const float* b1      = (const float*)d_in[4];
    const float* W3      = (const float*)d_in[7];
    const float* b3      = (const float*)d_in[8];
    float* out  = (float*)d_out;
    u32*   wsf  = (u32*)d_ws;
    float* part = (float*)(wsf + FRAG_U32);

    w3_prep<<<256, 256, 0, stream>>>(W3, wsf);
    htfe_main<<<NMB * KSPLIT, NT_MAIN, 0, stream>>>(x, start_L, idx_C, W1, b1, wsf, part);
    finish_reduce<<<256, 256, 0, stream>>>(part, b3, out);
}

// Round 19
// 32.143 us; speedup vs baseline: 1.0378x; 1.0378x over previous
//
#include <hip/hip_runtime.h>
#include <hip/hip_bf16.h>

// Problem constants
#define BB 64
#define LL 4096
#define CC 16
#define PL 128
#define PC 8
#define NPP 64
#define DD 64
#define TSTEP 0.01f

#define KSPLIT 4                    // lt-range split across blocks
#define LT_PER (PL / KSPLIT)        // 32 lt steps per block
#define NT_MAIN 256                 // 4 waves = 2 kk-halves x 2 patch-halves
#define NMB BB                      // one block-column per batch (64 patches)

#define FRAG_U32 (PL * 8 * 256)                       // 1 MB of W3 bf16 frags
#define SPLIT_STRIDE (NMB * 2 * 2 * 64 * 16)          // 262144 floats per split
#define PART_FLT (KSPLIT * SPLIT_STRIDE)              // 4 MB of f32 partials

typedef float f32x4  __attribute__((ext_vector_type(4)));
typedef float f32x16 __attribute__((ext_vector_type(16)));
typedef int   i32x4  __attribute__((ext_vector_type(4)));
typedef short s16x8  __attribute__((ext_vector_type(8)));
typedef unsigned int u32;

__device__ __forceinline__ float silu_f(float z) {      // z * rcp(1+exp(-z))
    return z * __builtin_amdgcn_rcpf(1.0f + __expf(-z));
}
__device__ __forceinline__ u32 pk(float lo, float hi) {
    __hip_bfloat162 p = __float22bfloat162_rn(float2{lo, hi});
    u32 r;
    __builtin_memcpy(&r, &p, 4);
    return r;
}
__device__ __forceinline__ s16x8 as8(i32x4 v) {
    s16x8 r;
    __builtin_memcpy(&r, &v, 16);
    return r;
}
// exchange: a keeps lo-half, gets b's lo into its hi; b gets a's old hi into its lo
__device__ __forceinline__ void plswap(u32& a, u32& b) {
    auto r = __builtin_amdgcn_permlane32_swap(a, b, false, false);
    u32 tmp[2];
    __builtin_memcpy(tmp, &r, 8);
    a = tmp[0]; b = tmp[1];
}

// ---- W3 (8192x64 f32) -> bf16 frags for mfma_32x32x16, in ws (1 MB) ----
// frag m = ltg*8 + kk*4 + ksub*2 + ns ; lane holds W3[k0 + 2j(+1)][ns*32 + (l&31)]
__global__ __launch_bounds__(256) void w3_prep(const float* __restrict__ W3,
                                               u32* __restrict__ wsf) {
    const int tid  = blockIdx.x * 256 + threadIdx.x;    // 65536 threads
    const int lane = tid & 63;
    const int m    = tid >> 6;                          // 0..1023
    const int ns   = m & 1;
    const int ksub = (m >> 1) & 1;
    const int kk   = (m >> 2) & 1;
    const int ltg  = m >> 3;
    const int k0   = ltg * 64 + kk * 32 + ksub * 16 + ((lane >> 5) << 3);
    const int col  = (ns << 5) + (lane & 31);
    u32 q[4];
    #pragma unroll
    for (int jj = 0; jj < 4; ++jj)
        q[jj] = pk(W3[(size_t)(k0 + 2 * jj)     * DD + col],
                   W3[(size_t)(k0 + 2 * jj + 1) * DD + col]);
    i32x4 v; v.x = (int)q[0]; v.y = (int)q[1]; v.z = (int)q[2]; v.w = (int)q[3];
    *(i32x4*)(wsf + (size_t)m * 256 + (lane << 2)) = v;
}

// ---------------------------- fused main kernel ----------------------------
// Best verified configuration (round 17: 32.2us, absmax 0.125). r18's staging
// pipeline regressed (VGPR pressure from 32 in-flight regs; staging already
// wave-overlapped) and was reverted.
// NOTE: no min-waves hint (round 4: forced spills). No device fences (round
// 11: cross-XCD L2 writeback cost ~130us).
__global__ __launch_bounds__(NT_MAIN) void htfe_main(
    const float* __restrict__ x, const int* __restrict__ start_L,
    const int* __restrict__ idx_C, const float* __restrict__ W1,
    const float* __restrict__ b1, const u32* __restrict__ wsf,
    float* __restrict__ part)
{
    // arena: rowbuf (512 rows x 17 f32 = 34816 B) during staging,
    //        kk-reduction accumulators (16384 B) after the main loop.
    __shared__ __align__(64) float arena[512 * 17];
    __shared__ __align__(16) u32   xq[LT_PER * 256];   // [lt][64 p][4] bf16 x packs (32 KB)
    __shared__ __align__(16) u32   cq[256];            // [64 p][4] bf16 c packs
    __shared__ int sStart[64];

    const int t    = threadIdx.x;
    const int lane = t & 63;
    const int w    = t >> 6;
    const int kk   = w >> 1;                 // K-half (which 32 of 64 dh per lt)
    const int ph   = w & 1;                  // patch half
    const int l31  = lane & 31;
    const bool loH = lane < 32;

    const int mb    = blockIdx.x & (NMB - 1);   // = batch b; XCD = mb%8 for all splits
    const int split = blockIdx.x >> 6;          // 0..3
    const int b     = mb;
    const int lt0   = split * LT_PER;

    if (t < 64) sStart[t] = start_L[b * NPP + t];
    const int pGat = t & 63;
    const i32x4 ciA = *(const i32x4*)(idx_C + (size_t)b * NPP * PC + pGat * 8);
    const i32x4 ciB = *(const i32x4*)(idx_C + (size_t)b * NPP * PC + pGat * 8 + 4);
    if (t < 64) {   // static c-feature B-frag region
        cq[t * 4 + 0] = pk((float)ciA.x, (float)ciA.y);
        cq[t * 4 + 1] = pk((float)ciA.z, (float)ciA.w);
        cq[t * 4 + 2] = pk((float)ciB.x, (float)ciB.y);
        cq[t * 4 + 3] = pk((float)ciB.z, (float)ciB.w);
    }
    __syncthreads();

    // ----- staging: 4 passes x 512 rows; coalesced row loads -> LDS gather -----
    #pragma unroll
    for (int pass = 0; pass < 4; ++pass) {
        #pragma unroll
        for (int q = 0; q < 8; ++q) {
            const int i    = q * 256 + t;       // 2048 float4 units
            const int row  = i >> 2;            // 0..511
            const int quad = i & 3;
            const int pp   = row & 63;
            const int gRow = sStart[pp] + lt0 + pass * 8 + (row >> 6);
            const f32x4 v = *(const f32x4*)(x + ((size_t)b * LL + (size_t)gRow) * CC + quad * 4);
            *(f32x4*)(arena + row * 17 + quad * 4) = v;
        }
        __syncthreads();
        #pragma unroll
        for (int g = 0; g < 2; ++g) {   // gather rows t and t+256 (same patch = t&63)
            const int rr = g * 256 + t;
            const float* rb = arena + rr * 17;
            int cis[8];
            cis[0]=ciA.x; cis[1]=ciA.y; cis[2]=ciA.z; cis[3]=ciA.w;
            cis[4]=ciB.x; cis[5]=ciB.y; cis[6]=ciB.z; cis[7]=ciB.w;
            u32 qh[4];
            #pragma unroll
            for (int c2 = 0; c2 < 4; ++c2)
                qh[c2] = pk(rb[cis[2 * c2]], rb[cis[2 * c2 + 1]]);
            u32* dst = xq + (pass * 8 + (rr >> 6)) * 256 + (rr & 63) * 4;
            i32x4 vh; vh.x=(int)qh[0]; vh.y=(int)qh[1]; vh.z=(int)qh[2]; vh.w=(int)qh[3];
            *(i32x4*)dst = vh;
        }
        __syncthreads();
    }

    const int p  = ph * 32 + l31;            // FULL patch id this lane's col owns
    const int dA = kk * 32 + l31;            // A row (d') this lane owns
    const float startPf = (float)sStart[p];

    // ----- GEMM1 A-fragment (W1^T slice), built once -----
    i32x4 a1f0;
    if (loH) {
        a1f0.x = (int)pk(W1[0 * DD + dA], W1[1 * DD + dA]);
        a1f0.y = (int)pk(W1[2 * DD + dA], W1[3 * DD + dA]);
        a1f0.z = (int)pk(W1[4 * DD + dA], W1[5 * DD + dA]);
        a1f0.w = (int)pk(W1[6 * DD + dA], W1[7 * DD + dA]);
    } else {
        a1f0.x = (int)pk(W1[ 9 * DD + dA], W1[10 * DD + dA]);
        a1f0.y = (int)pk(W1[11 * DD + dA], W1[12 * DD + dA]);
        a1f0.z = (int)pk(W1[13 * DD + dA], W1[14 * DD + dA]);
        a1f0.w = (int)pk(W1[15 * DD + dA], W1[16 * DD + dA]);
    }
    // f32 C-operand: hp = b1 + t*W1[8]
    f32x16 cb16, wt16;
    #pragma unroll
    for (int r = 0; r < 16; ++r) {
        const int dr = kk * 32 + (r & 3) + 8 * (r >> 2) + 4 * (lane >> 5);
        wt16[r] = W1[8 * DD + dr];
        cb16[r] = b1[dr];                    // bias ONLY (tf carries start)
    }

    // ----- main loop: no barriers, 5 MFMAs per lt -----
    f32x16 acc0 = {}, acc1 = {};
    const u32* bsrc = wsf + ((size_t)lt0 * 8 + (size_t)kk * 4) * 256 + (lane << 2);
    const u32* xrd     = loH ? (xq + p * 4) : (cq + p * 4);
    const int  xstride = loH ? 256 : 0;

    #pragma unroll 2
    for (int lt = 0; lt < LT_PER; ++lt) {
        const i32x4 bf00 = *(const i32x4*)(bsrc);         // ksub0 ns0
        const i32x4 bf01 = *(const i32x4*)(bsrc + 256);   // ksub0 ns1
        const i32x4 bf10 = *(const i32x4*)(bsrc + 512);   // ksub1 ns0
        const i32x4 bf11 = *(const i32x4*)(bsrc + 768);   // ksub1 ns1
        bsrc += 2048;

        const i32x4 rd = *(const i32x4*)xrd;              // x packs | c packs
        xrd += xstride;

        // GEMM1: hp = W1x^T * [x;c] + (b1 + t*W1[8]), t = (start+lt)*T in f32
        const float tf = (startPf + (float)(lt0 + lt)) * TSTEP;
        f32x16 hp;
        #pragma unroll
        for (int r = 0; r < 16; ++r) hp[r] = cb16[r] + tf * wt16[r];
        hp = __builtin_amdgcn_mfma_f32_32x32x16_bf16(as8(a1f0), as8(rd), hp, 0, 0, 0);

        // silu + pack to bf16 pairs (P[j] = rows (2j,2j+1) of this lane's quads)
        u32 P[8];
        #pragma unroll
        for (int j = 0; j < 8; ++j)
            P[j] = pk(silu_f(hp[2 * j]), silu_f(hp[2 * j + 1]));

        // fragment exchange: hpre C/D layout -> GEMM2 A-frag layout (verified r8)
        plswap(P[0], P[2]); plswap(P[1], P[3]);   // af0 = {P0,P1,P2,P3}
        plswap(P[4], P[6]); plswap(P[5], P[7]);   // af1 = {P4,P5,P6,P7}
        i32x4 af0; af0.x=(int)P[0]; af0.y=(int)P[1]; af0.z=(int)P[2]; af0.w=(int)P[3];
        i32x4 af1; af1.x=(int)P[4]; af1.y=(int)P[5]; af1.z=(int)P[6]; af1.w=(int)P[7];

        // GEMM2: accumulate both ns slices
        acc0 = __builtin_amdgcn_mfma_f32_32x32x16_bf16(as8(af0), as8(bf00), acc0, 0, 0, 0);
        acc0 = __builtin_amdgcn_mfma_f32_32x32x16_bf16(as8(af1), as8(bf10), acc0, 0, 0, 0);
        acc1 = __builtin_amdgcn_mfma_f32_32x32x16_bf16(as8(af0), as8(bf01), acc1, 0, 0, 0);
        acc1 = __builtin_amdgcn_mfma_f32_32x32x16_bf16(as8(af1), as8(bf11), acc1, 0, 0, 0);
    }

    // ----- kk-reduction in LDS (arena reused), then one coalesced partial store -----
    f32x16* redacc = (f32x16*)arena;    // [ph][2][64]
    __syncthreads();                    // rowbuf use done; re-purpose arena
    if (kk == 1) {
        redacc[(ph * 2 + 0) * 64 + lane] = acc0;
        redacc[(ph * 2 + 1) * 64 + lane] = acc1;
    }
    __syncthreads();
    if (kk == 0) {
        const f32x16 r0 = redacc[(ph * 2 + 0) * 64 + lane];
        const f32x16 r1 = redacc[(ph * 2 + 1) * 64 + lane];
        float* pd0 = part + ((((size_t)split * NMB + mb) * 2 + ph) * 2 + 0) * 1024 + (lane << 4);
        float* pd1 = pd0 + 1024;
        #pragma unroll
        for (int q = 0; q < 4; ++q) {
            f32x4 o0, o1;
            #pragma unroll
            for (int j = 0; j < 4; ++j) {
                o0[j] = acc0[q * 4 + j] + r0[q * 4 + j];
                o1[j] = acc1[q * 4 + j] + r1[q * 4 + j];
            }
            *(f32x4*)(pd0 + q * 4) = o0;
            *(f32x4*)(pd1 + q * 4) = o1;
        }
    }
}

// ------------- sum KSPLIT partials + bias + SiLU (writes out once) -------------
// Block bid handles mb = bid & 63 -> bid%8 == mb%8 == writer XCD (L2-resident read).
__global__ __launch_bounds__(256) void finish_reduce(const float* __restrict__ part,
                                                     const float* __restrict__ b3,
                                                     float* __restrict__ out) {
    const int bid   = blockIdx.x;            // 256
    const int mb    = bid & 63;
    const int chunk = bid >> 6;              // 0..3
    const int idx10 = chunk * 256 + threadIdx.x;   // 0..1023 within mb
    const int rq   = idx10 & 3;
    const int lane = (idx10 >> 2) & 63;
    const int ns   = (idx10 >> 8) & 1;
    const int ph   = (idx10 >> 9) & 1;
    const int l31  = lane & 31;
    const float* src = part + (((size_t)mb * 2 + ph) * 2 + ns) * 1024 + (lane << 4) + (rq << 2);
    f32x4 s = {0.f, 0.f, 0.f, 0.f};
    #pragma unroll
    for (int sp = 0; sp < KSPLIT; ++sp) {
        const f32x4 v = *(const f32x4*)(src + (size_t)sp * SPLIT_STRIDE);
        s.x += v.x; s.y += v.y; s.z += v.z; s.w += v.w;
    }
    const int col  = (ns << 5) + l31;
    const float bias = b3[col];
    #pragma unroll
    for (int j = 0; j < 4; ++j) {
        // verified 32x32 C/D layout: row=(r&3)+8*(r>>2)+4*(lane>>5), col=lane&31
        const int prow = ph * 32 + j + 8 * rq + 4 * (lane >> 5);
        out[(size_t)(mb * NPP + prow) * DD + col] = silu_f(s[j] + bias);
    }
}

extern "C" void kernel_launch(void* const* d_in, const int* in_sizes, int n_in,
                              void* d_out, int out_size, void* d_ws, size_t ws_size,
                              hipStream_t stream) {
    // inputs: x, start_L, idx_C, W1, b1, W2(unused), b2(unused), W3, b3
    const float* x       = (const float*)d_in[0];
    const int*   start_L = (const int*)  d_in[1];
    const int*   idx_C   = (const int*)  d_in[2];
    const float* W1      = (const float*)d_in[3];
    const float* b1      = (const float*)d_in[4];
    const float* W3      = (const float*)d_in[7];
    const float* b3      = (const float*)d_in[8];
    float* out  = (float*)d_out;
    u32*   wsf  = (u32*)d_ws;
    float* part = (float*)(wsf + FRAG_U32);

    w3_prep<<<256, 256, 0, stream>>>(W3, wsf);
    htfe_main<<<NMB * KSPLIT, NT_MAIN, 0, stream>>>(x, start_L, idx_C, W1, b1, wsf, part);
    finish_reduce<<<256, 256, 0, stream>>>(part, b3, out);
}